// Round 2
// baseline (3697.236 us; speedup 1.0000x reference)
//
#include <hip/hip_runtime.h>
#include <hip/hip_bf16.h>

// ---------------------------------------------------------------------------
// SimpleMPONetwork: h = relu(x@W_in^T + b_in); TT-SVD(W_mpo, f=16, bond=2);
// y = TT(h); h2 = relu(y + b_mpo); out = h2@W_out^T + b_out
//
// TT cores are rebuilt on-device every launch. We exploit basis-invariance of
// the final contraction: only the top-2 singular SUBSPACES matter, extracted
// via f64 Gram matrices + repeated squaring + orthogonal iteration.
// ---------------------------------------------------------------------------

// ---------------- ws layout (bytes) ----------------
// h      : 0          134217728   (8192x4096 f32, later overwritten by h2)
// P      : 134217728  33554432    (64 x 256 x 256 f64 syrk partials)
// A0     : 167772160  524288      (256x256 f64 ping)
// A1     : 168296448  524288      (256x256 f64 pong)
// scale  : 168820736  512         (1/trace)
// U1     : 168821248  4096        (256x2 f64)
// V2     : 168825344  4096        (256x2 f64)
// T2     : 168829440  1048576     (2x65536 f64)
// cores  : 169878016  8192        (G1f 512, G2f 1024, G3f 512 f32)

#define WS_H      0ull
#define WS_P      134217728ull
#define WS_A0     167772160ull
#define WS_A1     168296448ull
#define WS_SCALE  168820736ull
#define WS_U1     168821248ull
#define WS_V2     168825344ull
#define WS_T2     168829440ull
#define WS_CORES  169878016ull

// ---------------------------------------------------------------------------
// GEMM (NT): C[M,N] = A[M,K] * B[N,K]^T + bias[N], optional relu.
// 128x128 tile, BK=16, 256 threads, 8x8 per thread, f32.
// ---------------------------------------------------------------------------
template <int RELU>
__global__ __launch_bounds__(256) void gemm_nt(const float* __restrict__ A,
                                               const float* __restrict__ B,
                                               const float* __restrict__ bias,
                                               float* __restrict__ C,
                                               int M, int N, int K) {
  __shared__ float As[16 * 132];
  __shared__ float Bs[16 * 132];
  const int t = threadIdx.x;
  const int n0 = blockIdx.x * 128;
  const int m0 = blockIdx.y * 128;
  const int row = t >> 1;
  const int kseg = (t & 1) * 8;
  const int tm = t >> 4;
  const int tn = t & 15;

  const float* Ap = A + (size_t)(m0 + row) * K + kseg;
  const float* Bp = B + (size_t)(n0 + row) * K + kseg;

  float acc[8][8];
#pragma unroll
  for (int i = 0; i < 8; ++i)
#pragma unroll
    for (int j = 0; j < 8; ++j) acc[i][j] = 0.f;

  for (int k0 = 0; k0 < K; k0 += 16) {
    float4 a0 = *reinterpret_cast<const float4*>(Ap + k0);
    float4 a1 = *reinterpret_cast<const float4*>(Ap + k0 + 4);
    float4 b0 = *reinterpret_cast<const float4*>(Bp + k0);
    float4 b1 = *reinterpret_cast<const float4*>(Bp + k0 + 4);
    As[(kseg + 0) * 132 + row] = a0.x;
    As[(kseg + 1) * 132 + row] = a0.y;
    As[(kseg + 2) * 132 + row] = a0.z;
    As[(kseg + 3) * 132 + row] = a0.w;
    As[(kseg + 4) * 132 + row] = a1.x;
    As[(kseg + 5) * 132 + row] = a1.y;
    As[(kseg + 6) * 132 + row] = a1.z;
    As[(kseg + 7) * 132 + row] = a1.w;
    Bs[(kseg + 0) * 132 + row] = b0.x;
    Bs[(kseg + 1) * 132 + row] = b0.y;
    Bs[(kseg + 2) * 132 + row] = b0.z;
    Bs[(kseg + 3) * 132 + row] = b0.w;
    Bs[(kseg + 4) * 132 + row] = b1.x;
    Bs[(kseg + 5) * 132 + row] = b1.y;
    Bs[(kseg + 6) * 132 + row] = b1.z;
    Bs[(kseg + 7) * 132 + row] = b1.w;
    __syncthreads();
#pragma unroll
    for (int k = 0; k < 16; ++k) {
      float4 x0 = *reinterpret_cast<const float4*>(&As[k * 132 + tm * 8]);
      float4 x1 = *reinterpret_cast<const float4*>(&As[k * 132 + tm * 8 + 4]);
      float4 y0 = *reinterpret_cast<const float4*>(&Bs[k * 132 + tn * 8]);
      float4 y1 = *reinterpret_cast<const float4*>(&Bs[k * 132 + tn * 8 + 4]);
      float av[8] = {x0.x, x0.y, x0.z, x0.w, x1.x, x1.y, x1.z, x1.w};
      float bv[8] = {y0.x, y0.y, y0.z, y0.w, y1.x, y1.y, y1.z, y1.w};
#pragma unroll
      for (int i = 0; i < 8; ++i)
#pragma unroll
        for (int j = 0; j < 8; ++j) acc[i][j] += av[i] * bv[j];
    }
    __syncthreads();
  }

  float bv[8];
#pragma unroll
  for (int j = 0; j < 8; ++j) bv[j] = bias[n0 + tn * 8 + j];
#pragma unroll
  for (int i = 0; i < 8; ++i) {
    float o[8];
#pragma unroll
    for (int j = 0; j < 8; ++j) {
      float v = acc[i][j] + bv[j];
      if (RELU) v = fmaxf(v, 0.f);
      o[j] = v;
    }
    float* cp = C + (size_t)(m0 + tm * 8 + i) * N + n0 + tn * 8;
    *reinterpret_cast<float4*>(cp) = make_float4(o[0], o[1], o[2], o[3]);
    *reinterpret_cast<float4*>(cp + 4) = make_float4(o[4], o[5], o[6], o[7]);
  }
}

// ---------------------------------------------------------------------------
// M1 partial SYRK: M1[r,r'] = sum_c T1[r,c] T1[r',c], T1 row r=(o1,i1) is
// vec of W block [o1*256.., i1*256..]. Column set enumerated as (o_low,i_low).
// grid (4,4,64): 64x64 output tile per (bi,bj); slice s covers o_low in
// [4s,4s+4). f64 accumulate, partials to P[s].
// ---------------------------------------------------------------------------
__global__ __launch_bounds__(256) void m1_syrk(const float* __restrict__ W,
                                               double* __restrict__ P) {
  __shared__ float As[64 * 68];
  __shared__ float Bs[64 * 68];
  const int t = threadIdx.x;
  const int bi = blockIdx.x, bj = blockIdx.y, s = blockIdx.z;
  const int tm = t >> 4, tn = t & 15;
  const int rl = t >> 2, l4 = t & 3;

  const int rA = bi * 64 + rl;
  const int rB = bj * 64 + rl;
  const int o1A = rA >> 4, i1A = rA & 15;
  const int o1B = rB >> 4, i1B = rB & 15;

  double acc[4][4];
#pragma unroll
  for (int i = 0; i < 4; ++i)
#pragma unroll
    for (int j = 0; j < 4; ++j) acc[i][j] = 0.0;

  for (int ch = 0; ch < 16; ++ch) {
    const int o_low = s * 4 + (ch >> 2);
    const int ibase = (ch & 3) * 64;
    const float4* pa = reinterpret_cast<const float4*>(
        W + (size_t)(o1A * 256 + o_low) * 4096 + i1A * 256 + ibase);
    const float4* pb = reinterpret_cast<const float4*>(
        W + (size_t)(o1B * 256 + o_low) * 4096 + i1B * 256 + ibase);
#pragma unroll
    for (int q = 0; q < 4; ++q) {
      const int f = l4 + q * 4;  // 0..15 float4 within 64-col chunk
      float4 va = pa[f];
      float4 vb = pb[f];
      const int k0 = f * 4;
      As[(k0 + 0) * 68 + rl] = va.x;
      As[(k0 + 1) * 68 + rl] = va.y;
      As[(k0 + 2) * 68 + rl] = va.z;
      As[(k0 + 3) * 68 + rl] = va.w;
      Bs[(k0 + 0) * 68 + rl] = vb.x;
      Bs[(k0 + 1) * 68 + rl] = vb.y;
      Bs[(k0 + 2) * 68 + rl] = vb.z;
      Bs[(k0 + 3) * 68 + rl] = vb.w;
    }
    __syncthreads();
#pragma unroll 4
    for (int k = 0; k < 64; ++k) {
      float4 a4 = *reinterpret_cast<const float4*>(&As[k * 68 + tm * 4]);
      float4 b4 = *reinterpret_cast<const float4*>(&Bs[k * 68 + tn * 4]);
      float av[4] = {a4.x, a4.y, a4.z, a4.w};
      float bv[4] = {b4.x, b4.y, b4.z, b4.w};
#pragma unroll
      for (int i = 0; i < 4; ++i)
#pragma unroll
        for (int j = 0; j < 4; ++j)
          acc[i][j] += (double)av[i] * (double)bv[j];
    }
    __syncthreads();
  }
#pragma unroll
  for (int i = 0; i < 4; ++i)
#pragma unroll
    for (int j = 0; j < 4; ++j)
      P[(size_t)s * 65536 + (size_t)(bi * 64 + tm * 4 + i) * 256 +
        (bj * 64 + tn * 4 + j)] = acc[i][j];
}

__global__ void m1_reduce(const double* __restrict__ P, double* __restrict__ A0) {
  const int idx = blockIdx.x * 256 + threadIdx.x;
  double acc = 0.0;
  for (int s = 0; s < 64; ++s) acc += P[(size_t)s * 65536 + idx];
  A0[idx] = acc;
}

// ---------------------------------------------------------------------------
// trace + matrix squaring chain (256x256 f64), C = (A*inv_s)*(A*inv_s)
// ---------------------------------------------------------------------------
__global__ void trace256(const double* __restrict__ A, double* __restrict__ scale) {
  __shared__ double red[256];
  const int t = threadIdx.x;
  red[t] = A[t * 257];
  __syncthreads();
  for (int sft = 128; sft > 0; sft >>= 1) {
    if (t < sft) red[t] += red[t + sft];
    __syncthreads();
  }
  if (t == 0) scale[0] = 1.0 / red[0];
}

__global__ void sq256(const double* __restrict__ A, double* __restrict__ C,
                      const double* __restrict__ scale) {
  __shared__ double row[256];
  const int i = blockIdx.x, t = threadIdx.x;
  row[t] = A[(size_t)i * 256 + t];
  __syncthreads();
  const double inv = scale[0];
  double acc = 0.0;
  for (int k = 0; k < 256; ++k) acc += row[k] * A[(size_t)k * 256 + t];
  C[(size_t)i * 256 + t] = acc * inv * inv;
}

// ---------------------------------------------------------------------------
// Orthogonal (subspace) iteration on symmetric N (256x256 f64): top-2 basis.
// ---------------------------------------------------------------------------
__device__ inline double hash_init(int i, unsigned seed) {
  unsigned u = (unsigned)i * 2654435761u + seed * 40503u + 0x9E3779B9u;
  u ^= u >> 13;
  u *= 0x85EBCA6Bu;
  u ^= u >> 16;
  return ((double)(u & 0xFFFFFFu) / 16777216.0) - 0.5;
}

__global__ void subspace256(const double* __restrict__ Nm, double* __restrict__ out,
                            unsigned seed) {
  __shared__ double v0[256], v1[256];
  __shared__ double r0[256], r1[256], r2[256];
  const int t = threadIdx.x;
  v0[t] = hash_init(t, seed);
  v1[t] = hash_init(t + 1000, seed ^ 0x9E3779B9u);
  __syncthreads();
  for (int it = 0; it < 24; ++it) {
    double w0 = 0.0, w1 = 0.0;
    for (int k = 0; k < 256; ++k) {
      // N symmetric: N[t][k] == N[k][t]; read column-major for coalescing.
      const double nk = Nm[(size_t)k * 256 + t];
      w0 += nk * v0[k];
      w1 += nk * v1[k];
    }
    r0[t] = w0 * w0;
    r1[t] = w0 * w1;
    r2[t] = w1 * w1;
    __syncthreads();
    for (int sft = 128; sft > 0; sft >>= 1) {
      if (t < sft) {
        r0[t] += r0[t + sft];
        r1[t] += r1[t + sft];
        r2[t] += r2[t + sft];
      }
      __syncthreads();
    }
    const double s00 = r0[0], s01 = r1[0], s11 = r2[0];
    const double inv0 = 1.0 / sqrt(s00);
    const double c = s01 / s00;
    double n1sq = s11 - s01 * s01 / s00;
    n1sq = n1sq > 1e-300 ? n1sq : 1e-300;
    const double inv1 = 1.0 / sqrt(n1sq);
    const double q0 = w0 * inv0;
    const double q1 = (w1 - c * w0) * inv1;
    __syncthreads();  // everyone done reading r*[0] before next-iter writes
    v0[t] = q0;
    v1[t] = q1;
    __syncthreads();
  }
  out[t * 2 + 0] = v0[t];
  out[t * 2 + 1] = v1[t];
}

// ---------------------------------------------------------------------------
// T2[a,c] = sum_r U1[r,a] * T1[r,c]   (2 x 65536, f64)
// ---------------------------------------------------------------------------
__global__ void t2_build(const float* __restrict__ W, const double* __restrict__ U1,
                         double* __restrict__ T2) {
  __shared__ double U1s[512];
  const int t = threadIdx.x;
  U1s[t * 2] = U1[t * 2];
  U1s[t * 2 + 1] = U1[t * 2 + 1];
  __syncthreads();
  const int c = blockIdx.x * 256 + t;
  const int o2 = c >> 12, i2 = (c >> 8) & 15, o3 = (c >> 4) & 15, i3 = c & 15;
  const int wrb = o2 * 16 + o3;
  const int wcb = i2 * 16 + i3;
  double a0 = 0.0, a1 = 0.0;
  for (int r = 0; r < 256; ++r) {
    const int o1 = r >> 4, i1 = r & 15;
    const double w = (double)W[(size_t)(o1 * 256 + wrb) * 4096 + i1 * 256 + wcb];
    a0 += U1s[r * 2] * w;
    a1 += U1s[r * 2 + 1] * w;
  }
  T2[c] = a0;
  T2[65536 + c] = a1;
}

// ---------------------------------------------------------------------------
// M2r[m,m'] = sum_u M'[u,m] M'[u,m'];  M'[u,m] = T2[a, o2*4096+i2*256+m],
// u = a*256 + o2*16 + i2.
// ---------------------------------------------------------------------------
__global__ void m2r(const double* __restrict__ T2, double* __restrict__ M2) {
  __shared__ double col[512];
  const int t = threadIdx.x;
  const int m = blockIdx.x;
  for (int u = t; u < 512; u += 256) {
    const int a = u >> 8, o2 = (u >> 4) & 15, i2 = u & 15;
    col[u] = T2[(size_t)a * 65536 + o2 * 4096 + i2 * 256 + m];
  }
  __syncthreads();
  double acc = 0.0;
  for (int u = 0; u < 512; ++u) {
    const int a = u >> 8, o2 = (u >> 4) & 15, i2 = u & 15;
    acc += col[u] * T2[(size_t)a * 65536 + o2 * 4096 + i2 * 256 + t];
  }
  M2[(size_t)m * 256 + t] = acc;
}

// ---------------------------------------------------------------------------
// stage2 finish: Z = M' * V2 (512x2); U2 = orth(Z); G3 = U2^T M';
// pack f32 cores: G1f[I*32+J*2+a], G2f[(a*16+K)*32+L*2+b], G3f[b*256+M*16+N].
// ---------------------------------------------------------------------------
__global__ void stage2_finish(const double* __restrict__ T2,
                              const double* __restrict__ U1,
                              const double* __restrict__ V2,
                              float* __restrict__ cores) {
  __shared__ double V2s[512];
  __shared__ double U2s[1024];
  __shared__ double r0[256], r1[256], r2[256];
  const int t = threadIdx.x;
  V2s[t * 2] = V2[t * 2];
  V2s[t * 2 + 1] = V2[t * 2 + 1];
  __syncthreads();

  double z[2][2];
#pragma unroll
  for (int half = 0; half < 2; ++half) {
    const int u = t + half * 256;
    const int a = u >> 8, o2 = (u >> 4) & 15, i2 = u & 15;
    const double* rowp = T2 + (size_t)a * 65536 + o2 * 4096 + i2 * 256;
    double acc0 = 0.0, acc1 = 0.0;
    for (int m = 0; m < 256; ++m) {
      const double mv = rowp[m];
      acc0 += mv * V2s[m * 2];
      acc1 += mv * V2s[m * 2 + 1];
    }
    z[half][0] = acc0;
    z[half][1] = acc1;
  }
  r0[t] = z[0][0] * z[0][0] + z[1][0] * z[1][0];
  r1[t] = z[0][0] * z[0][1] + z[1][0] * z[1][1];
  r2[t] = z[0][1] * z[0][1] + z[1][1] * z[1][1];
  __syncthreads();
  for (int sft = 128; sft > 0; sft >>= 1) {
    if (t < sft) {
      r0[t] += r0[t + sft];
      r1[t] += r1[t + sft];
      r2[t] += r2[t + sft];
    }
    __syncthreads();
  }
  const double s00 = r0[0], s01 = r1[0], s11 = r2[0];
  const double inv0 = 1.0 / sqrt(s00);
  const double c = s01 / s00;
  double n1sq = s11 - s01 * s01 / s00;
  n1sq = n1sq > 1e-300 ? n1sq : 1e-300;
  const double inv1 = 1.0 / sqrt(n1sq);
#pragma unroll
  for (int half = 0; half < 2; ++half) {
    const int u = t + half * 256;
    U2s[u * 2 + 0] = z[half][0] * inv0;
    U2s[u * 2 + 1] = (z[half][1] - c * z[half][0]) * inv1;
  }
  __syncthreads();

  // G3[b][m], m = t
  double g30 = 0.0, g31 = 0.0;
  for (int u = 0; u < 512; ++u) {
    const int a = u >> 8, o2 = (u >> 4) & 15, i2 = u & 15;
    const double mv = T2[(size_t)a * 65536 + o2 * 4096 + i2 * 256 + t];
    g30 += U2s[u * 2] * mv;
    g31 += U2s[u * 2 + 1] * mv;
  }
  cores[1536 + t] = (float)g30;
  cores[1536 + 256 + t] = (float)g31;

  // G1f: idx = I*32 + J*2 + a  -> U1[(I*16+J)*2 + a]
#pragma unroll
  for (int e = 0; e < 2; ++e) {
    const int idx = t * 2 + e;
    const int I = idx >> 5, J = (idx >> 1) & 15, a = idx & 1;
    cores[idx] = (float)U1[(I * 16 + J) * 2 + a];
  }
  // G2f: g = (a*16+K)*32 + L*2 + b -> U2s[(a*256+K*16+L)*2 + b]
#pragma unroll
  for (int e = 0; e < 4; ++e) {
    const int g = t * 4 + e;
    const int aK = g >> 5;
    const int a = aK >> 4, K = aK & 15;
    const int L = (g >> 1) & 15, b = g & 1;
    cores[512 + g] = (float)U2s[(a * 256 + K * 16 + L) * 2 + b];
  }
}

// ---------------------------------------------------------------------------
// Per-sample TT apply: y = G1*G2*G3 * h_row; h2 = relu(y + b_mpo), in place.
// ---------------------------------------------------------------------------
__global__ __launch_bounds__(256) void mpo_apply(float* __restrict__ h,
                                                 const float* __restrict__ cores,
                                                 const float* __restrict__ b_mpo) {
  __shared__ float hrow[4096];
  __shared__ float t12[8192];
  __shared__ float G[2048];
  const int t = threadIdx.x;
  float* hg = h + (size_t)blockIdx.x * 4096;

  reinterpret_cast<float4*>(G)[t] = reinterpret_cast<const float4*>(cores)[t];
  reinterpret_cast<float4*>(G)[t + 256] =
      reinterpret_cast<const float4*>(cores)[t + 256];
#pragma unroll
  for (int q = 0; q < 4; ++q)
    reinterpret_cast<float4*>(hrow)[t + q * 256] =
        reinterpret_cast<const float4*>(hg)[t + q * 256];
  __syncthreads();

  const float* G1s = G;         // [I*32 + J*2 + a]
  const float* G2s = G + 512;   // [(a*16+K)*32 + L*2 + b]
  const float* G3s = G + 1536;  // [b*256 + M*16 + N]

  // phase 1: t = J*16 + L ; t1[(J*16+L)*32 + b*16+M] = sum_N G3 * h
  {
    float h16[16];
    const float4* hp =
        reinterpret_cast<const float4*>(hrow + (t >> 4) * 256 + (t & 15) * 16);
#pragma unroll
    for (int q = 0; q < 4; ++q) {
      float4 v = hp[q];
      h16[q * 4 + 0] = v.x;
      h16[q * 4 + 1] = v.y;
      h16[q * 4 + 2] = v.z;
      h16[q * 4 + 3] = v.w;
    }
    float outp[32];
#pragma unroll
    for (int bm = 0; bm < 32; ++bm) {
      const int base = (bm >> 4) * 256 + (bm & 15) * 16;
      float acc = 0.f;
#pragma unroll
      for (int N = 0; N < 16; ++N) acc += G3s[base + N] * h16[N];
      outp[bm] = acc;
    }
#pragma unroll
    for (int bm = 0; bm < 32; ++bm) t12[t * 32 + bm] = outp[bm];
  }
  __syncthreads();

  // phase 2: t = J*16 + M ; t2[J*512 + a*256 + K*16 + M] (overwrites t12)
  {
    const int J = t >> 4, M = t & 15;
    float tv[32];
#pragma unroll
    for (int L = 0; L < 16; ++L)
#pragma unroll
      for (int b = 0; b < 2; ++b)
        tv[L * 2 + b] = t12[(J * 16 + L) * 32 + b * 16 + M];
    float outp[32];
#pragma unroll
    for (int ak = 0; ak < 32; ++ak) {
      float acc = 0.f;
#pragma unroll
      for (int lb = 0; lb < 32; ++lb) acc += G2s[ak * 32 + lb] * tv[lb];
      outp[ak] = acc;
    }
    __syncthreads();  // all reads of t1 done before overwrite
#pragma unroll
    for (int ak = 0; ak < 32; ++ak) {
      const int a = ak >> 4, K = ak & 15;
      t12[J * 512 + a * 256 + K * 16 + M] = outp[ak];
    }
  }
  __syncthreads();

  // phase 3: t = K*16 + M ; y[I] = sum_{J,a} G1 * t2 ; relu(+b_mpo) -> hg
  {
    const int K = t >> 4, M = t & 15;
    float uv[32];
#pragma unroll
    for (int J = 0; J < 16; ++J)
#pragma unroll
      for (int a = 0; a < 2; ++a)
        uv[J * 2 + a] = t12[J * 512 + a * 256 + K * 16 + M];
#pragma unroll
    for (int I = 0; I < 16; ++I) {
      float acc = 0.f;
#pragma unroll
      for (int ja = 0; ja < 32; ++ja) acc += G1s[I * 32 + ja] * uv[ja];
      const int o = I * 256 + t;
      hg[o] = fmaxf(acc + b_mpo[o], 0.f);
    }
  }
}

// ---------------------------------------------------------------------------
extern "C" void kernel_launch(void* const* d_in, const int* in_sizes, int n_in,
                              void* d_out, int out_size, void* d_ws, size_t ws_size,
                              hipStream_t stream) {
  const float* x = (const float*)d_in[0];
  const float* W_in = (const float*)d_in[1];
  const float* b_in = (const float*)d_in[2];
  const float* W_mpo = (const float*)d_in[3];
  const float* b_mpo = (const float*)d_in[4];
  const float* W_out = (const float*)d_in[5];
  const float* b_out = (const float*)d_in[6];
  float* out = (float*)d_out;
  char* ws = (char*)d_ws;

  float* h = (float*)(ws + WS_H);
  double* P = (double*)(ws + WS_P);
  double* A0 = (double*)(ws + WS_A0);
  double* A1 = (double*)(ws + WS_A1);
  double* scale = (double*)(ws + WS_SCALE);
  double* U1 = (double*)(ws + WS_U1);
  double* V2 = (double*)(ws + WS_V2);
  double* T2 = (double*)(ws + WS_T2);
  float* cores = (float*)(ws + WS_CORES);

  // 1) h = relu(x @ W_in^T + b_in)
  gemm_nt<1><<<dim3(4096 / 128, 8192 / 128), 256, 0, stream>>>(
      x, W_in, b_in, h, 8192, 4096, 2048);

  // 2) M1 Gram of first unfolding
  m1_syrk<<<dim3(4, 4, 64), 256, 0, stream>>>(W_mpo, P);
  m1_reduce<<<256, 256, 0, stream>>>(P, A0);

  // 3) squaring chain (M1^1024) + orthogonal iteration -> U1 (top-2 basis)
  double* cur = A0;
  double* nxt = A1;
  for (int i = 0; i < 10; ++i) {
    trace256<<<1, 256, 0, stream>>>(cur, scale);
    sq256<<<256, 256, 0, stream>>>(cur, nxt, scale);
    double* tmp = cur; cur = nxt; nxt = tmp;
  }
  subspace256<<<1, 256, 0, stream>>>(cur, U1, 12345u);

  // 4) T2 = U1^T T1 ; second-stage Gram, chain, basis
  t2_build<<<256, 256, 0, stream>>>(W_mpo, U1, T2);
  m2r<<<256, 256, 0, stream>>>(T2, cur);
  for (int i = 0; i < 10; ++i) {
    trace256<<<1, 256, 0, stream>>>(cur, scale);
    sq256<<<256, 256, 0, stream>>>(cur, nxt, scale);
    double* tmp = cur; cur = nxt; nxt = tmp;
  }
  subspace256<<<1, 256, 0, stream>>>(cur, V2, 999331u);
  stage2_finish<<<1, 256, 0, stream>>>(T2, U1, V2, cores);

  // 5) per-sample TT apply + relu (in place on h)
  mpo_apply<<<8192, 256, 0, stream>>>(h, cores, b_mpo);

  // 6) out = h2 @ W_out^T + b_out
  gemm_nt<0><<<dim3(1024 / 128, 8192 / 128), 256, 0, stream>>>(
      h, W_out, b_out, out, 8192, 1024, 4096);
}

// Round 3
// 1653.408 us; speedup vs baseline: 2.2361x; 2.2361x over previous
//
#include <hip/hip_runtime.h>
#include <hip/hip_bf16.h>

// ---------------------------------------------------------------------------
// SimpleMPONetwork: h = relu(x@W_in^T + b_in); TT-SVD(W_mpo, f=16, bond=2);
// y = TT(h); h2 = relu(y + b_mpo); out = h2@W_out^T + b_out
//
// Round 2: both big GEMMs -> bf16x3 MFMA (hi/lo split, 3 mfma per pair,
// reg-staged f32->bf16). TT-SVD chain: coalesced t2_build, fused traces
// (f64 atomics), subspace iters 24->8.
// ---------------------------------------------------------------------------

// ---------------- ws layout (bytes) ---------------- (unchanged, <=170MB)
#define WS_H      0ull            // 8192x4096 f32 h (later h2 in place)
#define WS_P      134217728ull    // 64x256x256 f64 syrk partials
#define WS_A0     167772160ull    // 256x256 f64 ping
#define WS_A1     168296448ull    // 256x256 f64 pong
#define WS_SCALE  168820736ull    // 22 f64 trace slots (176B of 512B)
#define WS_U1     168821248ull    // 256x2 f64
#define WS_V2     168825344ull    // 256x2 f64
#define WS_T2     168829440ull    // 2x65536 f64
#define WS_CORES  169878016ull    // G1f 512, G2f 1024, G3f 512 f32

typedef short short8 __attribute__((ext_vector_type(8)));
typedef float f32x4 __attribute__((ext_vector_type(4)));

__device__ inline ushort bf16_trunc(float x) {
  return (ushort)(__builtin_bit_cast(unsigned int, x) >> 16);
}
__device__ inline float bf16_tof(ushort h) {
  return __builtin_bit_cast(float, ((unsigned int)h) << 16);
}

// ---------------------------------------------------------------------------
// bf16x3 MFMA GEMM (NT): C[M,N] = A[M,K]*B[N,K]^T + bias, optional relu.
// 128x128 tile, BK=32, 256 thr = 4 waves (2x2), each wave 64x64 = 4x4 frags
// of 16x16x32. A,B split into bf16 hi+lo; acc += ah*bh + ah*bl + al*bh.
// LDS tile layout: [koct][row][8] (koct = k>>3) -> conflict-minimal b128.
// Reg-staged: global f32 (coalesced) -> convert -> ds_write. Next-tile loads
// issued before MFMA section (latency hidden under compute).
// ---------------------------------------------------------------------------
template <int RELU>
__global__ __launch_bounds__(256) void gemm_bf16x3(
    const float* __restrict__ A, const float* __restrict__ B,
    const float* __restrict__ bias, float* __restrict__ C,
    int nbn, int nks, int K, int N) {
  __shared__ ushort ldsA[2 * 4096];  // [hi|lo], each 4096 = [4][128][8]
  __shared__ ushort ldsB[2 * 4096];
  const int t = threadIdx.x;
  const int lane = t & 63;
  const int w = t >> 6;
  const int wr = w >> 1, wc = w & 1;
  const int bm = blockIdx.x / nbn, bn = blockIdx.x % nbn;

  // staging map: row = t>>1 (0..127), khalf = t&1 -> k = khalf*16..+15
  const int srow = t >> 1;
  const int skh = t & 1;
  const float* Ap = A + (size_t)(bm * 128 + srow) * K + skh * 16;
  const float* Bp = B + (size_t)(bn * 128 + srow) * K + skh * 16;

  f32x4 acc[4][4];
#pragma unroll
  for (int m = 0; m < 4; ++m)
#pragma unroll
    for (int n = 0; n < 4; ++n) acc[m][n] = (f32x4){0.f, 0.f, 0.f, 0.f};

  float ar[16], br[16];
#pragma unroll
  for (int q = 0; q < 4; ++q) {
    float4 va = *reinterpret_cast<const float4*>(Ap + q * 4);
    ar[q * 4 + 0] = va.x; ar[q * 4 + 1] = va.y;
    ar[q * 4 + 2] = va.z; ar[q * 4 + 3] = va.w;
    float4 vb = *reinterpret_cast<const float4*>(Bp + q * 4);
    br[q * 4 + 0] = vb.x; br[q * 4 + 1] = vb.y;
    br[q * 4 + 2] = vb.z; br[q * 4 + 3] = vb.w;
  }

  for (int ks = 0; ks < nks; ++ks) {
    __syncthreads();  // prior iter's ds_reads done before overwrite
    // convert + ds_write: thread covers octets skh*2, skh*2+1 of row srow
#pragma unroll
    for (int half = 0; half < 2; ++half) {
      short8 hv, lv, hv2, lv2;
#pragma unroll
      for (int e = 0; e < 8; ++e) {
        float xa = ar[half * 8 + e];
        ushort ha = bf16_trunc(xa);
        hv[e] = (short)ha;
        lv[e] = (short)bf16_trunc(xa - bf16_tof(ha));
        float xb = br[half * 8 + e];
        ushort hb = bf16_trunc(xb);
        hv2[e] = (short)hb;
        lv2[e] = (short)bf16_trunc(xb - bf16_tof(hb));
      }
      const int off = (skh * 2 + half) * 1024 + srow * 8;
      *reinterpret_cast<short8*>(&ldsA[off]) = hv;
      *reinterpret_cast<short8*>(&ldsA[4096 + off]) = lv;
      *reinterpret_cast<short8*>(&ldsB[off]) = hv2;
      *reinterpret_cast<short8*>(&ldsB[4096 + off]) = lv2;
    }
    // prefetch next K-tile into regs (overlaps with MFMA below)
    if (ks + 1 < nks) {
#pragma unroll
      for (int q = 0; q < 4; ++q) {
        float4 va = *reinterpret_cast<const float4*>(Ap + (ks + 1) * 32 + q * 4);
        ar[q * 4 + 0] = va.x; ar[q * 4 + 1] = va.y;
        ar[q * 4 + 2] = va.z; ar[q * 4 + 3] = va.w;
        float4 vb = *reinterpret_cast<const float4*>(Bp + (ks + 1) * 32 + q * 4);
        br[q * 4 + 0] = vb.x; br[q * 4 + 1] = vb.y;
        br[q * 4 + 2] = vb.z; br[q * 4 + 3] = vb.w;
      }
    }
    __syncthreads();
    // frag reads: elem off = koct*1024 + row*8, koct = lane>>4
    const int fo = (lane >> 4) * 1024 + (lane & 15) * 8;
    short8 ah[4], al[4], bh[4], bl[4];
#pragma unroll
    for (int m = 0; m < 4; ++m) {
      const int off = fo + (wr * 64 + m * 16) * 8;
      ah[m] = *reinterpret_cast<const short8*>(&ldsA[off]);
      al[m] = *reinterpret_cast<const short8*>(&ldsA[4096 + off]);
    }
#pragma unroll
    for (int n = 0; n < 4; ++n) {
      const int off = fo + (wc * 64 + n * 16) * 8;
      bh[n] = *reinterpret_cast<const short8*>(&ldsB[off]);
      bl[n] = *reinterpret_cast<const short8*>(&ldsB[4096 + off]);
    }
#pragma unroll
    for (int m = 0; m < 4; ++m)
#pragma unroll
      for (int n = 0; n < 4; ++n) {
        acc[m][n] = __builtin_amdgcn_mfma_f32_16x16x32_bf16(ah[m], bh[n], acc[m][n], 0, 0, 0);
        acc[m][n] = __builtin_amdgcn_mfma_f32_16x16x32_bf16(ah[m], bl[n], acc[m][n], 0, 0, 0);
        acc[m][n] = __builtin_amdgcn_mfma_f32_16x16x32_bf16(al[m], bh[n], acc[m][n], 0, 0, 0);
      }
  }

  // epilogue: C/D layout (m89): col = lane&15, row = (lane>>4)*4 + reg
  const int col0 = bn * 128 + wc * 64 + (lane & 15);
  const int row0 = bm * 128 + wr * 64 + (lane >> 4) * 4;
#pragma unroll
  for (int n = 0; n < 4; ++n) {
    const int col = col0 + n * 16;
    const float bv = bias[col];
#pragma unroll
    for (int m = 0; m < 4; ++m) {
#pragma unroll
      for (int r = 0; r < 4; ++r) {
        float v = acc[m][n][r] + bv;
        if (RELU) v = fmaxf(v, 0.f);
        C[(size_t)(row0 + m * 16 + r) * N + col] = v;
      }
    }
  }
}

// ---------------------------------------------------------------------------
// M1 partial SYRK: M1[r,r'] = sum_c T1[r,c] T1[r',c]. f32 inner chunks (64),
// f64 across chunks (error ~1e-7 rel; Davis-Kahan subspace perturbation
// ~1e-6 << gap). grid (4,4,64), partials to P[s].
// ---------------------------------------------------------------------------
__global__ __launch_bounds__(256) void m1_syrk(const float* __restrict__ W,
                                               double* __restrict__ P) {
  __shared__ float As[64 * 68];
  __shared__ float Bs[64 * 68];
  const int t = threadIdx.x;
  const int bi = blockIdx.x, bj = blockIdx.y, s = blockIdx.z;
  const int tm = t >> 4, tn = t & 15;
  const int rl = t >> 2, l4 = t & 3;

  const int rA = bi * 64 + rl;
  const int rB = bj * 64 + rl;
  const int o1A = rA >> 4, i1A = rA & 15;
  const int o1B = rB >> 4, i1B = rB & 15;

  double accd[4][4];
#pragma unroll
  for (int i = 0; i < 4; ++i)
#pragma unroll
    for (int j = 0; j < 4; ++j) accd[i][j] = 0.0;

  for (int ch = 0; ch < 16; ++ch) {
    const int o_low = s * 4 + (ch >> 2);
    const int ibase = (ch & 3) * 64;
    const float4* pa = reinterpret_cast<const float4*>(
        W + (size_t)(o1A * 256 + o_low) * 4096 + i1A * 256 + ibase);
    const float4* pb = reinterpret_cast<const float4*>(
        W + (size_t)(o1B * 256 + o_low) * 4096 + i1B * 256 + ibase);
#pragma unroll
    for (int q = 0; q < 4; ++q) {
      const int f = l4 + q * 4;
      float4 va = pa[f];
      float4 vb = pb[f];
      const int k0 = f * 4;
      As[(k0 + 0) * 68 + rl] = va.x;
      As[(k0 + 1) * 68 + rl] = va.y;
      As[(k0 + 2) * 68 + rl] = va.z;
      As[(k0 + 3) * 68 + rl] = va.w;
      Bs[(k0 + 0) * 68 + rl] = vb.x;
      Bs[(k0 + 1) * 68 + rl] = vb.y;
      Bs[(k0 + 2) * 68 + rl] = vb.z;
      Bs[(k0 + 3) * 68 + rl] = vb.w;
    }
    __syncthreads();
    float accf[4][4];
#pragma unroll
    for (int i = 0; i < 4; ++i)
#pragma unroll
      for (int j = 0; j < 4; ++j) accf[i][j] = 0.f;
#pragma unroll 4
    for (int k = 0; k < 64; ++k) {
      float4 a4 = *reinterpret_cast<const float4*>(&As[k * 68 + tm * 4]);
      float4 b4 = *reinterpret_cast<const float4*>(&Bs[k * 68 + tn * 4]);
      float av[4] = {a4.x, a4.y, a4.z, a4.w};
      float bv[4] = {b4.x, b4.y, b4.z, b4.w};
#pragma unroll
      for (int i = 0; i < 4; ++i)
#pragma unroll
        for (int j = 0; j < 4; ++j) accf[i][j] += av[i] * bv[j];
    }
#pragma unroll
    for (int i = 0; i < 4; ++i)
#pragma unroll
      for (int j = 0; j < 4; ++j) accd[i][j] += (double)accf[i][j];
    __syncthreads();
  }
#pragma unroll
  for (int i = 0; i < 4; ++i)
#pragma unroll
    for (int j = 0; j < 4; ++j)
      P[(size_t)s * 65536 + (size_t)(bi * 64 + tm * 4 + i) * 256 +
        (bj * 64 + tn * 4 + j)] = accd[i][j];
}

// reduce partials; fused trace accumulation (f64 atomics -> tr[0])
__global__ void m1_reduce(const double* __restrict__ P, double* __restrict__ A0,
                          double* __restrict__ tr) {
  const int idx = blockIdx.x * 256 + threadIdx.x;
  double acc = 0.0;
  for (int s = 0; s < 64; ++s) acc += P[(size_t)s * 65536 + idx];
  A0[idx] = acc;
  if (idx % 257 == 0) atomicAdd(tr, acc);
}

// C = (A/trIn)^2; fused trace of C into trOut (atomics)
__global__ void sq256(const double* __restrict__ A, double* __restrict__ C,
                      const double* __restrict__ trIn, double* __restrict__ trOut) {
  __shared__ double row[256];
  const int i = blockIdx.x, t = threadIdx.x;
  row[t] = A[(size_t)i * 256 + t];
  __syncthreads();
  const double inv = 1.0 / trIn[0];
  double acc = 0.0;
  for (int k = 0; k < 256; ++k) acc += row[k] * A[(size_t)k * 256 + t];
  const double v = acc * inv * inv;
  C[(size_t)i * 256 + t] = v;
  if (t == i) atomicAdd(trOut, v);
}

// ---------------------------------------------------------------------------
// Orthogonal (subspace) iteration on symmetric N (256x256 f64): top-2 basis.
// Input is M^1024 -> 8 iters give effective power 8192 (typ. conv e^-49).
// ---------------------------------------------------------------------------
__device__ inline double hash_init(int i, unsigned seed) {
  unsigned u = (unsigned)i * 2654435761u + seed * 40503u + 0x9E3779B9u;
  u ^= u >> 13;
  u *= 0x85EBCA6Bu;
  u ^= u >> 16;
  return ((double)(u & 0xFFFFFFu) / 16777216.0) - 0.5;
}

__global__ void subspace256(const double* __restrict__ Nm, double* __restrict__ out,
                            unsigned seed) {
  __shared__ double v0[256], v1[256];
  __shared__ double r0[256], r1[256], r2[256];
  const int t = threadIdx.x;
  v0[t] = hash_init(t, seed);
  v1[t] = hash_init(t + 1000, seed ^ 0x9E3779B9u);
  __syncthreads();
  for (int it = 0; it < 8; ++it) {
    double w0 = 0.0, w1 = 0.0;
    for (int k = 0; k < 256; ++k) {
      const double nk = Nm[(size_t)k * 256 + t];  // symmetric: column read
      w0 += nk * v0[k];
      w1 += nk * v1[k];
    }
    r0[t] = w0 * w0;
    r1[t] = w0 * w1;
    r2[t] = w1 * w1;
    __syncthreads();
    for (int sft = 128; sft > 0; sft >>= 1) {
      if (t < sft) {
        r0[t] += r0[t + sft];
        r1[t] += r1[t + sft];
        r2[t] += r2[t + sft];
      }
      __syncthreads();
    }
    const double s00 = r0[0], s01 = r1[0], s11 = r2[0];
    const double inv0 = 1.0 / sqrt(s00);
    const double c = s01 / s00;
    double n1sq = s11 - s01 * s01 / s00;
    n1sq = n1sq > 1e-300 ? n1sq : 1e-300;
    const double inv1 = 1.0 / sqrt(n1sq);
    const double q0 = w0 * inv0;
    const double q1 = (w1 - c * w0) * inv1;
    __syncthreads();
    v0[t] = q0;
    v1[t] = q1;
    __syncthreads();
  }
  out[t * 2 + 0] = v0[t];
  out[t * 2 + 1] = v1[t];
}

// ---------------------------------------------------------------------------
// T2[a,c] = sum_r U1[r,a] * T1[r,c]. Coalesced rewrite: block b=(o2,o3) loops
// o1,i1 reading contiguous 1KB rows (col = i1*256 + t). W read exactly once.
// ---------------------------------------------------------------------------
__global__ __launch_bounds__(256) void t2_build(const float* __restrict__ W,
                                                const double* __restrict__ U1,
                                                double* __restrict__ T2) {
  __shared__ double U1s[512];
  const int t = threadIdx.x;
  U1s[t] = U1[t];
  U1s[256 + t] = U1[256 + t];
  __syncthreads();
  const int b = blockIdx.x;  // o2*16 + o3
  double a0 = 0.0, a1 = 0.0;
  for (int o1 = 0; o1 < 16; ++o1) {
    const float* rp = W + (size_t)(o1 * 256 + b) * 4096 + t;
#pragma unroll
    for (int i1 = 0; i1 < 16; ++i1) {
      const double wv = (double)rp[i1 * 256];
      const int r2 = (o1 * 16 + i1) * 2;
      a0 += U1s[r2] * wv;
      a1 += U1s[r2 + 1] * wv;
    }
  }
  const int c = (b >> 4) * 4096 + (t >> 4) * 256 + (b & 15) * 16 + (t & 15);
  T2[c] = a0;
  T2[65536 + c] = a1;
}

// ---------------------------------------------------------------------------
// M2r[m,m'] = sum_u M'[u,m] M'[u,m']; fused trace -> trOut.
// ---------------------------------------------------------------------------
__global__ void m2r(const double* __restrict__ T2, double* __restrict__ M2,
                    double* __restrict__ trOut) {
  __shared__ double col[512];
  const int t = threadIdx.x;
  const int m = blockIdx.x;
  for (int u = t; u < 512; u += 256) {
    const int a = u >> 8, o2 = (u >> 4) & 15, i2 = u & 15;
    col[u] = T2[(size_t)a * 65536 + o2 * 4096 + i2 * 256 + m];
  }
  __syncthreads();
  double acc = 0.0;
  for (int u = 0; u < 512; ++u) {
    const int a = u >> 8, o2 = (u >> 4) & 15, i2 = u & 15;
    acc += col[u] * T2[(size_t)a * 65536 + o2 * 4096 + i2 * 256 + t];
  }
  M2[(size_t)m * 256 + t] = acc;
  if (t == m) atomicAdd(trOut, acc);
}

// ---------------------------------------------------------------------------
// stage2 finish: Z = M' * V2; U2 = orth(Z); G3 = U2^T M'; pack f32 cores.
// ---------------------------------------------------------------------------
__global__ void stage2_finish(const double* __restrict__ T2,
                              const double* __restrict__ U1,
                              const double* __restrict__ V2,
                              float* __restrict__ cores) {
  __shared__ double V2s[512];
  __shared__ double U2s[1024];
  __shared__ double r0[256], r1[256], r2[256];
  const int t = threadIdx.x;
  V2s[t * 2] = V2[t * 2];
  V2s[t * 2 + 1] = V2[t * 2 + 1];
  __syncthreads();

  double z[2][2];
#pragma unroll
  for (int half = 0; half < 2; ++half) {
    const int u = t + half * 256;
    const int a = u >> 8, o2 = (u >> 4) & 15, i2 = u & 15;
    const double* rowp = T2 + (size_t)a * 65536 + o2 * 4096 + i2 * 256;
    double acc0 = 0.0, acc1 = 0.0;
    for (int m = 0; m < 256; ++m) {
      const double mv = rowp[m];
      acc0 += mv * V2s[m * 2];
      acc1 += mv * V2s[m * 2 + 1];
    }
    z[half][0] = acc0;
    z[half][1] = acc1;
  }
  r0[t] = z[0][0] * z[0][0] + z[1][0] * z[1][0];
  r1[t] = z[0][0] * z[0][1] + z[1][0] * z[1][1];
  r2[t] = z[0][1] * z[0][1] + z[1][1] * z[1][1];
  __syncthreads();
  for (int sft = 128; sft > 0; sft >>= 1) {
    if (t < sft) {
      r0[t] += r0[t + sft];
      r1[t] += r1[t + sft];
      r2[t] += r2[t + sft];
    }
    __syncthreads();
  }
  const double s00 = r0[0], s01 = r1[0], s11 = r2[0];
  const double inv0 = 1.0 / sqrt(s00);
  const double c = s01 / s00;
  double n1sq = s11 - s01 * s01 / s00;
  n1sq = n1sq > 1e-300 ? n1sq : 1e-300;
  const double inv1 = 1.0 / sqrt(n1sq);
#pragma unroll
  for (int half = 0; half < 2; ++half) {
    const int u = t + half * 256;
    U2s[u * 2 + 0] = z[half][0] * inv0;
    U2s[u * 2 + 1] = (z[half][1] - c * z[half][0]) * inv1;
  }
  __syncthreads();

  double g30 = 0.0, g31 = 0.0;
  for (int u = 0; u < 512; ++u) {
    const int a = u >> 8, o2 = (u >> 4) & 15, i2 = u & 15;
    const double mv = T2[(size_t)a * 65536 + o2 * 4096 + i2 * 256 + t];
    g30 += U2s[u * 2] * mv;
    g31 += U2s[u * 2 + 1] * mv;
  }
  cores[1536 + t] = (float)g30;
  cores[1536 + 256 + t] = (float)g31;

#pragma unroll
  for (int e = 0; e < 2; ++e) {
    const int idx = t * 2 + e;
    const int I = idx >> 5, J = (idx >> 1) & 15, a = idx & 1;
    cores[idx] = (float)U1[(I * 16 + J) * 2 + a];
  }
#pragma unroll
  for (int e = 0; e < 4; ++e) {
    const int g = t * 4 + e;
    const int aK = g >> 5;
    const int a = aK >> 4, K = aK & 15;
    const int L = (g >> 1) & 15, b = g & 1;
    cores[512 + g] = (float)U2s[(a * 256 + K * 16 + L) * 2 + b];
  }
}

// ---------------------------------------------------------------------------
// Per-sample TT apply: y = G1*G2*G3 * h_row; h2 = relu(y + b_mpo), in place.
// ---------------------------------------------------------------------------
__global__ __launch_bounds__(256) void mpo_apply(float* __restrict__ h,
                                                 const float* __restrict__ cores,
                                                 const float* __restrict__ b_mpo) {
  __shared__ float hrow[4096];
  __shared__ float t12[8192];
  __shared__ float G[2048];
  const int t = threadIdx.x;
  float* hg = h + (size_t)blockIdx.x * 4096;

  reinterpret_cast<float4*>(G)[t] = reinterpret_cast<const float4*>(cores)[t];
  reinterpret_cast<float4*>(G)[t + 256] =
      reinterpret_cast<const float4*>(cores)[t + 256];
#pragma unroll
  for (int q = 0; q < 4; ++q)
    reinterpret_cast<float4*>(hrow)[t + q * 256] =
        reinterpret_cast<const float4*>(hg)[t + q * 256];
  __syncthreads();

  const float* G1s = G;         // [I*32 + J*2 + a]
  const float* G2s = G + 512;   // [(a*16+K)*32 + L*2 + b]
  const float* G3s = G + 1536;  // [b*256 + M*16 + N]

  // phase 1: t = J*16 + L ; t1[(J*16+L)*32 + b*16+M] = sum_N G3 * h
  {
    float h16[16];
    const float4* hp =
        reinterpret_cast<const float4*>(hrow + (t >> 4) * 256 + (t & 15) * 16);
#pragma unroll
    for (int q = 0; q < 4; ++q) {
      float4 v = hp[q];
      h16[q * 4 + 0] = v.x;
      h16[q * 4 + 1] = v.y;
      h16[q * 4 + 2] = v.z;
      h16[q * 4 + 3] = v.w;
    }
    float outp[32];
#pragma unroll
    for (int bm = 0; bm < 32; ++bm) {
      const int base = (bm >> 4) * 256 + (bm & 15) * 16;
      float acc = 0.f;
#pragma unroll
      for (int N = 0; N < 16; ++N) acc += G3s[base + N] * h16[N];
      outp[bm] = acc;
    }
#pragma unroll
    for (int bm = 0; bm < 32; ++bm) t12[t * 32 + bm] = outp[bm];
  }
  __syncthreads();

  // phase 2: t = J*16 + M ; t2[J*512 + a*256 + K*16 + M]
  {
    const int J = t >> 4, M = t & 15;
    float tv[32];
#pragma unroll
    for (int L = 0; L < 16; ++L)
#pragma unroll
      for (int b = 0; b < 2; ++b)
        tv[L * 2 + b] = t12[(J * 16 + L) * 32 + b * 16 + M];
    float outp[32];
#pragma unroll
    for (int ak = 0; ak < 32; ++ak) {
      float acc = 0.f;
#pragma unroll
      for (int lb = 0; lb < 32; ++lb) acc += G2s[ak * 32 + lb] * tv[lb];
      outp[ak] = acc;
    }
    __syncthreads();
#pragma unroll
    for (int ak = 0; ak < 32; ++ak) {
      const int a = ak >> 4, K = ak & 15;
      t12[J * 512 + a * 256 + K * 16 + M] = outp[ak];
    }
  }
  __syncthreads();

  // phase 3: t = K*16 + M ; y[I] = sum_{J,a} G1 * t2 ; relu(+b_mpo) -> hg
  {
    const int K = t >> 4, M = t & 15;
    float uv[32];
#pragma unroll
    for (int J = 0; J < 16; ++J)
#pragma unroll
      for (int a = 0; a < 2; ++a)
        uv[J * 2 + a] = t12[J * 512 + a * 256 + K * 16 + M];
#pragma unroll
    for (int I = 0; I < 16; ++I) {
      float acc = 0.f;
#pragma unroll
      for (int ja = 0; ja < 32; ++ja) acc += G1s[I * 32 + ja] * uv[ja];
      const int o = I * 256 + t;
      hg[o] = fmaxf(acc + b_mpo[o], 0.f);
    }
  }
}

// ---------------------------------------------------------------------------
extern "C" void kernel_launch(void* const* d_in, const int* in_sizes, int n_in,
                              void* d_out, int out_size, void* d_ws, size_t ws_size,
                              hipStream_t stream) {
  const float* x = (const float*)d_in[0];
  const float* W_in = (const float*)d_in[1];
  const float* b_in = (const float*)d_in[2];
  const float* W_mpo = (const float*)d_in[3];
  const float* b_mpo = (const float*)d_in[4];
  const float* W_out = (const float*)d_in[5];
  const float* b_out = (const float*)d_in[6];
  float* out = (float*)d_out;
  char* ws = (char*)d_ws;

  float* h = (float*)(ws + WS_H);
  double* P = (double*)(ws + WS_P);
  double* A0 = (double*)(ws + WS_A0);
  double* A1 = (double*)(ws + WS_A1);
  double* TR = (double*)(ws + WS_SCALE);  // 22 trace slots
  double* U1 = (double*)(ws + WS_U1);
  double* V2 = (double*)(ws + WS_V2);
  double* T2 = (double*)(ws + WS_T2);
  float* cores = (float*)(ws + WS_CORES);

  hipMemsetAsync(TR, 0, 512, stream);

  // 1) h = relu(x @ W_in^T + b_in)   [bf16x3 MFMA]
  gemm_bf16x3<1><<<2048, 256, 0, stream>>>(x, W_in, b_in, h, 32, 64, 2048, 4096);

  // 2) M1 Gram of first unfolding
  m1_syrk<<<dim3(4, 4, 64), 256, 0, stream>>>(W_mpo, P);
  m1_reduce<<<256, 256, 0, stream>>>(P, A0, TR);

  // 3) squaring chain (M1^1024) + subspace iteration -> U1
  double* cur = A0;
  double* nxt = A1;
  for (int i = 0; i < 10; ++i) {
    sq256<<<256, 256, 0, stream>>>(cur, nxt, TR + i, TR + i + 1);
    double* tmp = cur; cur = nxt; nxt = tmp;
  }
  subspace256<<<1, 256, 0, stream>>>(cur, U1, 12345u);

  // 4) T2 = U1^T T1 ; stage-2 Gram, chain, basis
  t2_build<<<256, 256, 0, stream>>>(W_mpo, U1, T2);
  m2r<<<256, 256, 0, stream>>>(T2, cur, TR + 11);
  for (int i = 0; i < 10; ++i) {
    sq256<<<256, 256, 0, stream>>>(cur, nxt, TR + 11 + i, TR + 12 + i);
    double* tmp = cur; cur = nxt; nxt = tmp;
  }
  subspace256<<<1, 256, 0, stream>>>(cur, V2, 999331u);
  stage2_finish<<<1, 256, 0, stream>>>(T2, U1, V2, cores);

  // 5) per-sample TT apply + relu (in place on h)
  mpo_apply<<<8192, 256, 0, stream>>>(h, cores, b_mpo);

  // 6) out = h2 @ W_out^T + b_out   [bf16x3 MFMA]
  gemm_bf16x3<0><<<512, 256, 0, stream>>>(h, W_out, b_out, out, 8, 128, 4096, 1024);
}